// Round 2
// baseline (1170.452 us; speedup 1.0000x reference)
//
#include <hip/hip_runtime.h>
#include <hip/hip_bf16.h>
#include <stdint.h>

// out[M,N] = x[M,K] @ W'[N,K]^T + bias[N], W' = W + SCALE*(loraB @ loraA)
// M = 16384 (B*S), N = 4096, K = 4096. SCALE = 16/16 = 1.0.
#define M_DIM 16384
#define N_DIM 4096
#define K_DIM 4096
#define LORA_SCALE 1.0f
#define BK 64                      // k-tile depth: 32 MFMA per barrier pair
#define CVT_BLOCKS (M_DIM * K_DIM / 2048)  // 32768 blocks of 256 thr x 8 elem

typedef _Float16 half8 __attribute__((ext_vector_type(8)));
typedef float f32x4 __attribute__((ext_vector_type(4)));

// ---------------------------------------------------------------------------
// Fused pre-pass: blocks [0, CVT_BLOCKS) convert x fp32 -> f16;
// blocks [CVT_BLOCKS, CVT_BLOCKS+256) build W' = W + loraB@loraA in f16.
// ---------------------------------------------------------------------------
__global__ __launch_bounds__(256) void pre_kernel(const float* __restrict__ x,
                                                  const float* __restrict__ W,
                                                  const float* __restrict__ lA,
                                                  const float* __restrict__ lB,
                                                  _Float16* __restrict__ xb,
                                                  _Float16* __restrict__ wp) {
    __shared__ float A_lds[16][256];
    __shared__ float B_lds[256];
    const int t = threadIdx.x;

    if (blockIdx.x < CVT_BLOCKS) {
        size_t base = ((size_t)blockIdx.x * 256 + (size_t)t) * 8;
        f32x4 a = *(const f32x4*)(x + base);
        f32x4 b = *(const f32x4*)(x + base + 4);
        half8 h;
        h[0] = (_Float16)a[0]; h[1] = (_Float16)a[1];
        h[2] = (_Float16)a[2]; h[3] = (_Float16)a[3];
        h[4] = (_Float16)b[0]; h[5] = (_Float16)b[1];
        h[6] = (_Float16)b[2]; h[7] = (_Float16)b[3];
        *(half8*)(xb + base) = h;
        return;
    }

    const int n0 = (blockIdx.x - CVT_BLOCKS) * 16;
    // loraB is [N,16] row-major: rows n0..n0+15 are 256 contiguous floats.
    B_lds[t] = lB[(size_t)n0 * 16 + t];

    for (int kc = 0; kc < 16; ++kc) {
        const int k = kc * 256 + t;
        __syncthreads();
#pragma unroll
        for (int r = 0; r < 16; ++r) A_lds[r][t] = lA[(size_t)r * K_DIM + k];
        __syncthreads();
#pragma unroll 4
        for (int row = 0; row < 16; ++row) {
            float acc = W[(size_t)(n0 + row) * K_DIM + k];
            float dot = 0.f;
#pragma unroll
            for (int r = 0; r < 16; ++r) dot += B_lds[row * 16 + r] * A_lds[r][t];
            wp[(size_t)(n0 + row) * K_DIM + k] = (_Float16)(acc + LORA_SCALE * dot);
        }
    }
}

// ---------------------------------------------------------------------------
// GEMM: C[m,n] = sum_k A[m,k]*B[n,k] + bias[n].
// 128x128 block tile, BK=64, 4 waves (2x2), each wave 64x64 via 4x4 of
// 16x16x32 f16 MFMA, 2 k-steps per tile. XOR-swizzled LDS (chunk col ^= row&7)
// keeps ds_read_b128 at the free 2-way bank-conflict level while staging via
// global_load_lds (LDS dest contiguous; only global src addr is permuted).
// ---------------------------------------------------------------------------
__device__ inline void load_lds16(const void* g, void* l) {
    __builtin_amdgcn_global_load_lds(
        (const __attribute__((address_space(1))) unsigned int*)(uintptr_t)g,
        (__attribute__((address_space(3))) unsigned int*)(uintptr_t)l,
        16, 0, 0);
}

__global__ __launch_bounds__(256) void gemm_bt_kernel(const _Float16* __restrict__ A,
                                                      const _Float16* __restrict__ B,
                                                      const float* __restrict__ bias,
                                                      float* __restrict__ C) {
    __shared__ _Float16 As[128 * BK];   // 16 KB
    __shared__ _Float16 Bs[128 * BK];   // 16 KB

    const int tid  = threadIdx.x;
    const int lane = tid & 63;
    const int quad = lane >> 4;   // 0..3: k-slice of fragment / row-group of C
    const int r16  = lane & 15;   // A: m, B: n, C: col n
    const int wave = tid >> 6;
    const int wm   = wave >> 1;
    const int wn   = wave & 1;

    const int m0 = blockIdx.y * 128;
    const int n0 = blockIdx.x * 128;

    // Staging: 1024 16B-chunks per matrix; thread owns chunks c = tid + 256*p.
    // LDS position c holds global chunk (row = c>>3, col = (c&7) ^ (row&7)).
    const _Float16* gA[4];
    const _Float16* gB[4];
    _Float16* lA[4];
    _Float16* lB[4];
#pragma unroll
    for (int p = 0; p < 4; ++p) {
        const int c    = tid + 256 * p;
        const int row  = c >> 3;
        const int colc = (c & 7) ^ (row & 7);   // XOR swizzle
        gA[p] = A + (size_t)(m0 + row) * K_DIM + colc * 8;
        gB[p] = B + (size_t)(n0 + row) * K_DIM + colc * 8;
        lA[p] = &As[c * 8];
        lB[p] = &Bs[c * 8];
    }

    f32x4 acc[4][4] = {};

    for (int kt = 0; kt < K_DIM / BK; ++kt) {
#pragma unroll
        for (int p = 0; p < 4; ++p) load_lds16(gA[p], lA[p]);
#pragma unroll
        for (int p = 0; p < 4; ++p) load_lds16(gB[p], lB[p]);
#pragma unroll
        for (int p = 0; p < 4; ++p) { gA[p] += BK; gB[p] += BK; }

        __syncthreads();  // drain staging; tiles visible

#pragma unroll
        for (int s = 0; s < 2; ++s) {   // two k-steps of 32 within the BK=64 tile
            half8 af[4], bf[4];
#pragma unroll
            for (int i = 0; i < 4; ++i) {
                const int row = wm * 64 + i * 16 + r16;
                const int cc  = (s * 4 + quad) ^ (r16 & 7);  // un-swizzle
                af[i] = *(const half8*)&As[row * BK + cc * 8];
            }
#pragma unroll
            for (int j = 0; j < 4; ++j) {
                const int row = wn * 64 + j * 16 + r16;
                const int cc  = (s * 4 + quad) ^ (r16 & 7);
                bf[j] = *(const half8*)&Bs[row * BK + cc * 8];
            }
#pragma unroll
            for (int i = 0; i < 4; ++i)
#pragma unroll
                for (int j = 0; j < 4; ++j)
                    acc[i][j] = __builtin_amdgcn_mfma_f32_16x16x32_f16(af[i], bf[j],
                                                                       acc[i][j], 0, 0, 0);
        }

        __syncthreads();  // all reads done before next overwrite
    }

    // Epilogue: C/D layout col = lane&15, row = quad*4 + reg.
#pragma unroll
    for (int j = 0; j < 4; ++j) {
        const int n = n0 + wn * 64 + j * 16 + r16;
        const float bv = bias[n];
#pragma unroll
        for (int i = 0; i < 4; ++i) {
            const int mbase = m0 + wm * 64 + i * 16 + quad * 4;
#pragma unroll
            for (int r = 0; r < 4; ++r) {
                C[(size_t)(mbase + r) * N_DIM + n] = acc[i][j][r] + bv;
            }
        }
    }
}

// ---------------------------------------------------------------------------
extern "C" void kernel_launch(void* const* d_in, const int* in_sizes, int n_in,
                              void* d_out, int out_size, void* d_ws, size_t ws_size,
                              hipStream_t stream) {
    const float* x      = (const float*)d_in[0];  // [M,K] fp32
    const float* weight = (const float*)d_in[1];  // [N,K] fp32
    const float* bias   = (const float*)d_in[2];  // [N] fp32
    const float* lora_A = (const float*)d_in[3];  // [16,K] fp32
    const float* lora_B = (const float*)d_in[4];  // [N,16] fp32
    float* out = (float*)d_out;

    _Float16* xb = (_Float16*)d_ws;                                       // 128 MiB
    _Float16* wp = (_Float16*)((char*)d_ws + (size_t)M_DIM * K_DIM * 2);  // +32 MiB

    pre_kernel<<<dim3(CVT_BLOCKS + N_DIM / 16), dim3(256), 0, stream>>>(
        x, weight, lora_A, lora_B, xb, wp);
    gemm_bt_kernel<<<dim3(N_DIM / 128, M_DIM / 128), dim3(256), 0, stream>>>(
        xb, wp, bias, out);
}